// Round 5
// baseline (217.251 us; speedup 1.0000x reference)
//
#include <hip/hip_runtime.h>
#include <hip/hip_bf16.h>

#define NB 1024
#define LQ 20
#define LD 200
#define E4 32      // 128 floats / 4
#define NK 21
#define NTILE 13   // ceil(208/16) j-tiles of 16 d-cols

typedef __attribute__((ext_vector_type(8))) short bf16x8;   // 8 bf16 = 4 VGPRs
typedef __attribute__((ext_vector_type(4))) float f32x4;

// Packed f32->bf16 RNE via the cast path (compiler emits v_cvt_pk_bf16_f32).
// __hip_bfloat162 is not trivially copyable on this ROCm -> memcpy the bits.
__device__ __forceinline__ unsigned cvt2(float lo, float hi) {
    __hip_bfloat162 h = __float22bfloat162_rn(make_float2(lo, hi));
    unsigned u;
    __builtin_memcpy(&u, &h, 4);
    return u;
}
__device__ __forceinline__ float lo2f(unsigned p) { return __builtin_bit_cast(float, p << 16); }
__device__ __forceinline__ float hi2f(unsigned p) { return __builtin_bit_cast(float, p & 0xFFFF0000u); }

__device__ __forceinline__ bf16x8 make_frag(float4 f0, float4 f1, float& sq) {
    union { unsigned u[4]; bf16x8 v; } r;
    r.u[0] = cvt2(f0.x, f0.y);
    r.u[1] = cvt2(f0.z, f0.w);
    r.u[2] = cvt2(f1.x, f1.y);
    r.u[3] = cvt2(f1.z, f1.w);
    #pragma unroll
    for (int i = 0; i < 4; ++i) {
        const float a = lo2f(r.u[i]); sq = fmaf(a, a, sq);
        const float b = hi2f(r.u[i]); sq = fmaf(b, b, sq);
    }
    return r.v;
}

__device__ __forceinline__ float fast_exp2(float x) {
#if __has_builtin(__builtin_amdgcn_exp2f)
    return __builtin_amdgcn_exp2f(x);
#else
    return __expf(x * 0.69314718056f);
#endif
}

// Gaussian kernel bank via geometric ladder: phi_k = exp(-50 (m-mu_k)^2),
// mu_k = 0.1k - 0.95. phi_10 direct, then outward recurrences (ratio shrinks
// by e^-1 per step). Underflow->0 only in true tails => exactly harmless.
// 3 exp2 + ~60 VALU replaces 21 exp2. k=20 is the exact kernel (sigma=1e-3).
__device__ __forceinline__ void rbf_accum(float m, float* S) {
    const float x = m - 0.05f;                       // m - mu_10
    const float p = fast_exp2(-72.13475204f * x * x);
    S[10] += p;
    float u = fast_exp2(fmaf(m, 14.4269504089f, -1.44269504089f)); // exp(10m-1)
    float q = p;
    #pragma unroll
    for (int k = 11; k <= 19; ++k) {
        q *= u;
        S[k] += q;
        u *= 0.36787944117f;                         // e^-1
    }
    float v = fast_exp2(m * -14.4269504089f);        // exp(-10m)
    q = p;
    #pragma unroll
    for (int k = 9; k >= 0; --k) {
        q *= v;
        S[k] += q;
        v *= 0.36787944117f;
    }
    const float d = m - 1.0f;
    S[20] += fast_exp2(-721347.5204f * d * d);       // exact kernel, sigma=1e-3
}

// One block per batch item, BOTH preds fused: waves {0,1}->pred0, {2,3}->pred1.
// Grid = 1024 = exactly 4 blocks/CU -> fully resident, zero dispatch tail.
// Per wave: alternating j-tiles (7/6); barrier-free gather->MFMA->in-reg RBF.
__global__ __launch_bounds__(256, 4) void knrm_main(
    const int* __restrict__ q1, const int* __restrict__ d1,
    const int* __restrict__ q2, const int* __restrict__ d2,
    const float* __restrict__ emb,
    const float* __restrict__ W1, const float* __restrict__ b1,
    const float* __restrict__ W2, const float* __restrict__ b2,
    const float* __restrict__ W3, const float* __restrict__ b3,
    float* __restrict__ out)        // [NB]
{
    __shared__ float sPhiW[4][LQ][NK];   // per-wave partial sums, 6.72 KB
    __shared__ float sX[2][NK];
    __shared__ float sH1[2][10];
    __shared__ float sH2[2][5];

    const int b    = blockIdx.x;
    const int t    = threadIdx.x;
    const int lane = t & 63, wave = t >> 6;
    const int pred = wave >> 1, wv = wave & 1;   // wv: which half of the tiles
    const int c    = lane & 15, quad = lane >> 4;
    const int* __restrict__ qi = pred ? q2 : q1;
    const int* __restrict__ di = pred ? d2 : d1;
    const float4* emb4 = (const float4*)emb;

    // ---- prefetch all ids up front ----
    int qid[2];
    #pragma unroll
    for (int Mt = 0; Mt < 2; ++Mt) {
        int row = Mt * 16 + c; row = row < LQ ? row : LQ - 1;
        qid[Mt] = qi[b * LQ + row];
    }
    int idv[7];
    #pragma unroll
    for (int tt = 0; tt < 7; ++tt) {
        const int tile = wv + 2 * tt;
        int j = tile * 16 + c; j = j < LD ? j : LD - 1;
        idv[tt] = (tile < NTILE) ? di[b * LD + j] : 0;
    }

    // ---- Q fragments (B operand): cols i = c (Mt0) / 16+c (Mt1) ----
    bf16x8 aF[2][4];
    float rqA = 0.f, rqB = 0.f;
    #pragma unroll
    for (int Mt = 0; Mt < 2; ++Mt) {
        const float4* qb = emb4 + (size_t)(unsigned)qid[Mt] * E4;
        float qs = 0.f;
        #pragma unroll
        for (int ks = 0; ks < 4; ++ks) {
            float4 f0 = qb[ks * 8 + quad * 2];
            float4 f1 = qb[ks * 8 + quad * 2 + 1];
            aF[Mt][ks] = make_frag(f0, f1, qs);
        }
        if (Mt == 1 && c >= LQ - 16) {           // pad q-rows 20..31 -> exact zeros
            #pragma unroll
            for (int ks = 0; ks < 4; ++ks) aF[Mt][ks] = (bf16x8)0;
            qs = 0.f;
        }
        qs += __shfl_xor(qs, 16);                // sum k-chunks across quads
        qs += __shfl_xor(qs, 32);
        const float rq = rsqrtf(qs + 1e-6f);
        if (Mt == 0) rqA = rq; else rqB = rq;
    }

    // ---- per-lane RBF accumulators ----
    // S0: i = c, j = tile*16 + quad*4 + r
    // S1: redistributed; lane L owns (i = 16+((L>>2)&3), j = tile*16+(L>>4)*4+(L&3))
    float S0[NK], S1[NK];
    #pragma unroll
    for (int k = 0; k < NK; ++k) { S0[k] = 0.f; S1[k] = 0.f; }

    #pragma unroll
    for (int tt = 0; tt < 7; ++tt) {
        const int tile = wv + 2 * tt;            // wave-uniform
        if (tile >= NTILE) break;

        // gather 16 d-rows (lane c owns row tile*16+c; quads split the 128 dims)
        const float4* db = emb4 + (size_t)(unsigned)idv[tt] * E4;
        bf16x8 bF[4];
        float dsq = 0.f;
        #pragma unroll
        for (int ks = 0; ks < 4; ++ks) {
            float4 f0 = db[ks * 8 + quad * 2];
            float4 f1 = db[ks * 8 + quad * 2 + 1];
            bF[ks] = make_frag(f0, f1, dsq);
        }
        if (tile * 16 + c >= LD) {               // pad d-rows -> exact zeros => m==0
            #pragma unroll
            for (int ks = 0; ks < 4; ++ks) bF[ks] = (bf16x8)0;
            dsq = 0.f;
        }
        dsq += __shfl_xor(dsq, 16);
        dsq += __shfl_xor(dsq, 32);
        const float rdc = rsqrtf(dsq + 1e-6f);   // rd for row tile*16+c
        float rdv[4];
        #pragma unroll
        for (int r = 0; r < 4; ++r) rdv[r] = __shfl(rdc, quad * 4 + r);

        // MFMA swapped: C col = lane&15 = q-row i, C row = quad*4+reg = d-col j
        f32x4 acc0 = {0.f, 0.f, 0.f, 0.f};
        f32x4 acc1 = {0.f, 0.f, 0.f, 0.f};
        #pragma unroll
        for (int ks = 0; ks < 4; ++ks) {
            acc0 = __builtin_amdgcn_mfma_f32_16x16x32_bf16(bF[ks], aF[0][ks], acc0, 0, 0, 0);
            acc1 = __builtin_amdgcn_mfma_f32_16x16x32_bf16(bF[ks], aF[1][ks], acc1, 0, 0, 0);
        }

        // acc0: i = c real for all lanes; 4 rbf per lane
        #pragma unroll
        for (int r = 0; r < 4; ++r)
            rbf_accum(acc0[r] * rdv[r] * rqA, S0);

        // acc1: only cols c<4 real (i=16..19) -> 64 useful values per tile.
        // Redistribute so each lane runs exactly ONE rbf_accum.
        float m1[4];
        #pragma unroll
        for (int r = 0; r < 4; ++r) m1[r] = acc1[r] * rdv[r] * rqB;
        const int src = (lane & 48) | ((lane >> 2) & 3);
        const float g0 = __shfl(m1[0], src);
        const float g1 = __shfl(m1[1], src);
        const float g2 = __shfl(m1[2], src);
        const float g3 = __shfl(m1[3], src);
        const int rsel = lane & 3;
        const float mv = (rsel == 0) ? g0 : (rsel == 1) ? g1 : (rsel == 2) ? g2 : g3;
        rbf_accum(mv, S1);
    }

    // ---- reductions ----
    #pragma unroll
    for (int k = 0; k < NK; ++k) {
        S0[k] += __shfl_xor(S0[k], 16);
        S0[k] += __shfl_xor(S0[k], 32);
        S1[k] += __shfl_xor(S1[k], 1);
        S1[k] += __shfl_xor(S1[k], 2);
        S1[k] += __shfl_xor(S1[k], 16);
        S1[k] += __shfl_xor(S1[k], 32);
    }
    if (quad == 0) {
        #pragma unroll
        for (int k = 0; k < NK; ++k) sPhiW[wave][c][k] = S0[k];
    }
    if ((lane & 51) == 0) {                       // lanes 0,4,8,12 -> i = 16..19
        #pragma unroll
        for (int k = 0; k < NK; ++k) sPhiW[wave][16 + (lane >> 2)][k] = S1[k];
    }
    __syncthreads();

    // ---- epilogue: waves 0/1 handle pred 0/1 in parallel ----
    const int ew = t >> 6, et = t & 63;

    // log1p + sum over i; subtract the 8 padded-j rows (each added phi_k(0))
    if (ew < 2 && et < NK) {
        const float mu_t = 0.1f * (float)et - 0.95f;
        const float pad  = (et < 20) ? 8.0f * fast_exp2(-72.13475204f * mu_t * mu_t) : 0.0f;
        float s = 0.f;
        #pragma unroll
        for (int i = 0; i < LQ; ++i) {
            const float v = sPhiW[2 * ew][i][et] + sPhiW[2 * ew + 1][i][et] - pad;
            s += __logf(1.0f + v);
        }
        sX[ew][et] = fmaxf(s, 0.f);   // relu (guards tiny negative from pad cancel)
    }
    __syncthreads();

    if (ew < 2 && et < 10) {
        float v = b1[et];
        #pragma unroll
        for (int k = 0; k < NK; ++k) v += W1[et * NK + k] * sX[ew][k];
        sH1[ew][et] = fmaxf(v, 0.f);
    }
    __syncthreads();

    if (ew < 2 && et < 5) {
        float v = b2[et];
        #pragma unroll
        for (int k = 0; k < 10; ++k) v += W2[et * 10 + k] * sH1[ew][k];
        sH2[ew][et] = fmaxf(v, 0.f);
    }
    __syncthreads();

    if (t == 0) {
        float l0 = b3[0], l1 = b3[0];
        #pragma unroll
        for (int k = 0; k < 5; ++k) {
            l0 += W3[k] * sH2[0][k];
            l1 += W3[k] * sH2[1][k];
        }
        out[b] = 1.0f / (1.0f + __expf(l1 - l0));   // sigmoid(l0 - l1)
    }
}

extern "C" void kernel_launch(void* const* d_in, const int* in_sizes, int n_in,
                              void* d_out, int out_size, void* d_ws, size_t ws_size,
                              hipStream_t stream) {
    knrm_main<<<NB, 256, 0, stream>>>(
        (const int*)d_in[0], (const int*)d_in[1],
        (const int*)d_in[2], (const int*)d_in[3],
        (const float*)d_in[4],
        (const float*)d_in[5], (const float*)d_in[6],
        (const float*)d_in[7], (const float*)d_in[8],
        (const float*)d_in[9], (const float*)d_in[10],
        (float*)d_out);
}

// Round 6
// 148.675 us; speedup vs baseline: 1.4612x; 1.4612x over previous
//
#include <hip/hip_runtime.h>
#include <hip/hip_bf16.h>

#define NB 1024
#define LQ 20
#define LD 200
#define E4 32      // 128 floats / 4
#define NK 21
#define NTILE 13   // ceil(208/16) j-tiles of 16 d-cols

typedef __attribute__((ext_vector_type(8))) short bf16x8;   // 8 bf16 = 4 VGPRs
typedef __attribute__((ext_vector_type(4))) float f32x4;

// Packed f32->bf16 RNE via the cast path (compiler emits v_cvt_pk_bf16_f32).
// __hip_bfloat162 is not trivially copyable on this ROCm -> memcpy the bits.
__device__ __forceinline__ unsigned cvt2(float lo, float hi) {
    __hip_bfloat162 h = __float22bfloat162_rn(make_float2(lo, hi));
    unsigned u;
    __builtin_memcpy(&u, &h, 4);
    return u;
}
__device__ __forceinline__ float lo2f(unsigned p) { return __builtin_bit_cast(float, p << 16); }
__device__ __forceinline__ float hi2f(unsigned p) { return __builtin_bit_cast(float, p & 0xFFFF0000u); }

__device__ __forceinline__ bf16x8 make_frag(float4 f0, float4 f1, float& sq) {
    union { unsigned u[4]; bf16x8 v; } r;
    r.u[0] = cvt2(f0.x, f0.y);
    r.u[1] = cvt2(f0.z, f0.w);
    r.u[2] = cvt2(f1.x, f1.y);
    r.u[3] = cvt2(f1.z, f1.w);
    #pragma unroll
    for (int i = 0; i < 4; ++i) {
        const float a = lo2f(r.u[i]); sq = fmaf(a, a, sq);
        const float b = hi2f(r.u[i]); sq = fmaf(b, b, sq);
    }
    return r.v;
}

__device__ __forceinline__ float fast_exp2(float x) {
#if __has_builtin(__builtin_amdgcn_exp2f)
    return __builtin_amdgcn_exp2f(x);
#else
    return __expf(x * 0.69314718056f);
#endif
}

// Gaussian kernel bank via geometric ladder: phi_k = exp(-50 (m-mu_k)^2),
// mu_k = 0.1k - 0.95. phi_10 direct, then outward recurrences (ratio shrinks
// by e^-1 per step). Underflow->0 only in true tails => exactly harmless.
// 3 exp2 + ~60 VALU replaces 21 exp2. k=20 is the exact kernel (sigma=1e-3).
__device__ __forceinline__ void rbf_accum(float m, float* S) {
    const float x = m - 0.05f;                       // m - mu_10
    const float p = fast_exp2(-72.13475204f * x * x);
    S[10] += p;
    float u = fast_exp2(fmaf(m, 14.4269504089f, -1.44269504089f)); // exp(10m-1)
    float q = p;
    #pragma unroll
    for (int k = 11; k <= 19; ++k) {
        q *= u;
        S[k] += q;
        u *= 0.36787944117f;                         // e^-1
    }
    float v = fast_exp2(m * -14.4269504089f);        // exp(-10m)
    q = p;
    #pragma unroll
    for (int k = 9; k >= 0; --k) {
        q *= v;
        S[k] += q;
        v *= 0.36787944117f;
    }
    const float d = m - 1.0f;
    S[20] += fast_exp2(-721347.5204f * d * d);       // exact kernel, sigma=1e-3
}

// One block per batch item, BOTH preds fused: waves {0,1}->pred0, {2,3}->pred1.
// Grid = 1024 = exactly 4 blocks/CU -> fully resident, zero dispatch tail.
// launch_bounds(256,2): empirical VGPR cap ~= 256/arg on this compiler;
// arg 4 capped at 64 VGPR and spilled ~310 MB/dispatch to scratch (R5).
// Cap 128 fits the ~110-reg live set spill-free AND still allows 4 blocks/CU.
__global__ __launch_bounds__(256, 2) void knrm_main(
    const int* __restrict__ q1, const int* __restrict__ d1,
    const int* __restrict__ q2, const int* __restrict__ d2,
    const float* __restrict__ emb,
    const float* __restrict__ W1, const float* __restrict__ b1,
    const float* __restrict__ W2, const float* __restrict__ b2,
    const float* __restrict__ W3, const float* __restrict__ b3,
    float* __restrict__ out)        // [NB]
{
    __shared__ float sPhiW[4][LQ][NK];   // per-wave partial sums, 6.72 KB
    __shared__ float sX[2][NK];
    __shared__ float sH1[2][10];
    __shared__ float sH2[2][5];

    const int b    = blockIdx.x;
    const int t    = threadIdx.x;
    const int lane = t & 63, wave = t >> 6;
    const int pred = wave >> 1, wv = wave & 1;   // wv: which half of the tiles
    const int c    = lane & 15, quad = lane >> 4;
    const int* __restrict__ qi = pred ? q2 : q1;
    const int* __restrict__ di = pred ? d2 : d1;
    const float4* emb4 = (const float4*)emb;

    // ---- prefetch all ids up front ----
    int qid[2];
    #pragma unroll
    for (int Mt = 0; Mt < 2; ++Mt) {
        int row = Mt * 16 + c; row = row < LQ ? row : LQ - 1;
        qid[Mt] = qi[b * LQ + row];
    }
    int idv[7];
    #pragma unroll
    for (int tt = 0; tt < 7; ++tt) {
        const int tile = wv + 2 * tt;
        int j = tile * 16 + c; j = j < LD ? j : LD - 1;
        idv[tt] = (tile < NTILE) ? di[b * LD + j] : 0;
    }

    // ---- Q fragments (B operand): cols i = c (Mt0) / 16+c (Mt1) ----
    bf16x8 aF[2][4];
    float rqA = 0.f, rqB = 0.f;
    #pragma unroll
    for (int Mt = 0; Mt < 2; ++Mt) {
        const float4* qb = emb4 + (size_t)(unsigned)qid[Mt] * E4;
        float qs = 0.f;
        #pragma unroll
        for (int ks = 0; ks < 4; ++ks) {
            float4 f0 = qb[ks * 8 + quad * 2];
            float4 f1 = qb[ks * 8 + quad * 2 + 1];
            aF[Mt][ks] = make_frag(f0, f1, qs);
        }
        if (Mt == 1 && c >= LQ - 16) {           // pad q-rows 20..31 -> exact zeros
            #pragma unroll
            for (int ks = 0; ks < 4; ++ks) aF[Mt][ks] = (bf16x8)0;
            qs = 0.f;
        }
        qs += __shfl_xor(qs, 16);                // sum k-chunks across quads
        qs += __shfl_xor(qs, 32);
        const float rq = rsqrtf(qs + 1e-6f);
        if (Mt == 0) rqA = rq; else rqB = rq;
    }

    // ---- per-lane RBF accumulators ----
    // S0: i = c, j = tile*16 + quad*4 + r
    // S1: redistributed; lane L owns (i = 16+((L>>2)&3), j = tile*16+(L>>4)*4+(L&3))
    float S0[NK], S1[NK];
    #pragma unroll
    for (int k = 0; k < NK; ++k) { S0[k] = 0.f; S1[k] = 0.f; }

    #pragma unroll
    for (int tt = 0; tt < 7; ++tt) {
        const int tile = wv + 2 * tt;            // wave-uniform
        if (tile >= NTILE) break;

        // gather 16 d-rows (lane c owns row tile*16+c; quads split the 128 dims)
        const float4* db = emb4 + (size_t)(unsigned)idv[tt] * E4;
        bf16x8 bF[4];
        float dsq = 0.f;
        #pragma unroll
        for (int ks = 0; ks < 4; ++ks) {
            float4 f0 = db[ks * 8 + quad * 2];
            float4 f1 = db[ks * 8 + quad * 2 + 1];
            bF[ks] = make_frag(f0, f1, dsq);
        }
        if (tile * 16 + c >= LD) {               // pad d-rows -> exact zeros => m==0
            #pragma unroll
            for (int ks = 0; ks < 4; ++ks) bF[ks] = (bf16x8)0;
            dsq = 0.f;
        }
        dsq += __shfl_xor(dsq, 16);
        dsq += __shfl_xor(dsq, 32);
        const float rdc = rsqrtf(dsq + 1e-6f);   // rd for row tile*16+c
        float rdv[4];
        #pragma unroll
        for (int r = 0; r < 4; ++r) rdv[r] = __shfl(rdc, quad * 4 + r);

        // MFMA swapped: C col = lane&15 = q-row i, C row = quad*4+reg = d-col j
        f32x4 acc0 = {0.f, 0.f, 0.f, 0.f};
        f32x4 acc1 = {0.f, 0.f, 0.f, 0.f};
        #pragma unroll
        for (int ks = 0; ks < 4; ++ks) {
            acc0 = __builtin_amdgcn_mfma_f32_16x16x32_bf16(bF[ks], aF[0][ks], acc0, 0, 0, 0);
            acc1 = __builtin_amdgcn_mfma_f32_16x16x32_bf16(bF[ks], aF[1][ks], acc1, 0, 0, 0);
        }

        // acc0: i = c real for all lanes; 4 rbf per lane
        #pragma unroll
        for (int r = 0; r < 4; ++r)
            rbf_accum(acc0[r] * rdv[r] * rqA, S0);

        // acc1: only cols c<4 real (i=16..19) -> 64 useful values per tile.
        // Redistribute so each lane runs exactly ONE rbf_accum.
        float m1[4];
        #pragma unroll
        for (int r = 0; r < 4; ++r) m1[r] = acc1[r] * rdv[r] * rqB;
        const int src = (lane & 48) | ((lane >> 2) & 3);
        const float g0 = __shfl(m1[0], src);
        const float g1 = __shfl(m1[1], src);
        const float g2 = __shfl(m1[2], src);
        const float g3 = __shfl(m1[3], src);
        const int rsel = lane & 3;
        const float mv = (rsel == 0) ? g0 : (rsel == 1) ? g1 : (rsel == 2) ? g2 : g3;
        rbf_accum(mv, S1);
    }

    // ---- reductions ----
    #pragma unroll
    for (int k = 0; k < NK; ++k) {
        S0[k] += __shfl_xor(S0[k], 16);
        S0[k] += __shfl_xor(S0[k], 32);
        S1[k] += __shfl_xor(S1[k], 1);
        S1[k] += __shfl_xor(S1[k], 2);
        S1[k] += __shfl_xor(S1[k], 16);
        S1[k] += __shfl_xor(S1[k], 32);
    }
    if (quad == 0) {
        #pragma unroll
        for (int k = 0; k < NK; ++k) sPhiW[wave][c][k] = S0[k];
    }
    if ((lane & 51) == 0) {                       // lanes 0,4,8,12 -> i = 16..19
        #pragma unroll
        for (int k = 0; k < NK; ++k) sPhiW[wave][16 + (lane >> 2)][k] = S1[k];
    }
    __syncthreads();

    // ---- epilogue: waves 0/1 handle pred 0/1 in parallel ----
    const int ew = t >> 6, et = t & 63;

    // log1p + sum over i; subtract the 8 padded-j rows (each added phi_k(0))
    if (ew < 2 && et < NK) {
        const float mu_t = 0.1f * (float)et - 0.95f;
        const float pad  = (et < 20) ? 8.0f * fast_exp2(-72.13475204f * mu_t * mu_t) : 0.0f;
        float s = 0.f;
        #pragma unroll
        for (int i = 0; i < LQ; ++i) {
            const float v = sPhiW[2 * ew][i][et] + sPhiW[2 * ew + 1][i][et] - pad;
            s += __logf(1.0f + v);
        }
        sX[ew][et] = fmaxf(s, 0.f);   // relu (guards tiny negative from pad cancel)
    }
    __syncthreads();

    if (ew < 2 && et < 10) {
        float v = b1[et];
        #pragma unroll
        for (int k = 0; k < NK; ++k) v += W1[et * NK + k] * sX[ew][k];
        sH1[ew][et] = fmaxf(v, 0.f);
    }
    __syncthreads();

    if (ew < 2 && et < 5) {
        float v = b2[et];
        #pragma unroll
        for (int k = 0; k < 10; ++k) v += W2[et * 10 + k] * sH1[ew][k];
        sH2[ew][et] = fmaxf(v, 0.f);
    }
    __syncthreads();

    if (t == 0) {
        float l0 = b3[0], l1 = b3[0];
        #pragma unroll
        for (int k = 0; k < 5; ++k) {
            l0 += W3[k] * sH2[0][k];
            l1 += W3[k] * sH2[1][k];
        }
        out[b] = 1.0f / (1.0f + __expf(l1 - l0));   // sigmoid(l0 - l1)
    }
}

extern "C" void kernel_launch(void* const* d_in, const int* in_sizes, int n_in,
                              void* d_out, int out_size, void* d_ws, size_t ws_size,
                              hipStream_t stream) {
    knrm_main<<<NB, 256, 0, stream>>>(
        (const int*)d_in[0], (const int*)d_in[1],
        (const int*)d_in[2], (const int*)d_in[3],
        (const float*)d_in[4],
        (const float*)d_in[5], (const float*)d_in[6],
        (const float*)d_in[7], (const float*)d_in[8],
        (const float*)d_in[9], (const float*)d_in[10],
        (float*)d_out);
}

// Round 7
// 137.727 us; speedup vs baseline: 1.5774x; 1.0795x over previous
//
#include <hip/hip_runtime.h>
#include <hip/hip_bf16.h>

#define NB 1024
#define LQ 20
#define LD 200
#define E4 32      // 128 floats / 4
#define NK 21
#define NTILE 13   // ceil(208/16) j-tiles of 16 d-cols

typedef __attribute__((ext_vector_type(8))) short bf16x8;   // 8 bf16 = 4 VGPRs
typedef __attribute__((ext_vector_type(4))) float f32x4;

// Packed f32->bf16 RNE via the cast path (compiler emits v_cvt_pk_bf16_f32).
__device__ __forceinline__ unsigned cvt2(float lo, float hi) {
    __hip_bfloat162 h = __float22bfloat162_rn(make_float2(lo, hi));
    unsigned u;
    __builtin_memcpy(&u, &h, 4);
    return u;
}

__device__ __forceinline__ bf16x8 pack8(float4 f0, float4 f1) {
    union { unsigned u[4]; bf16x8 v; } r;
    r.u[0] = cvt2(f0.x, f0.y);
    r.u[1] = cvt2(f0.z, f0.w);
    r.u[2] = cvt2(f1.x, f1.y);
    r.u[3] = cvt2(f1.z, f1.w);
    return r.v;
}

// Norm accumulation from RAW f32 (matches reference, which norms the
// un-rounded embeddings; also deletes the bf16 back-convert bit-ops).
__device__ __forceinline__ float sq8(float4 f0, float4 f1, float s) {
    s = fmaf(f0.x, f0.x, s); s = fmaf(f0.y, f0.y, s);
    s = fmaf(f0.z, f0.z, s); s = fmaf(f0.w, f0.w, s);
    s = fmaf(f1.x, f1.x, s); s = fmaf(f1.y, f1.y, s);
    s = fmaf(f1.z, f1.z, s); s = fmaf(f1.w, f1.w, s);
    return s;
}

__device__ __forceinline__ float fast_exp2(float x) {
#if __has_builtin(__builtin_amdgcn_exp2f)
    return __builtin_amdgcn_exp2f(x);
#else
    return __expf(x * 0.69314718056f);
#endif
}

// Gaussian kernel bank via geometric ladder (see R2): 3 exp2 + ~60 VALU.
// m == 0.0 exactly contributes exactly phi_k(0) -> subtracted in epilogue.
__device__ __forceinline__ void rbf_accum(float m, float* S) {
    const float x = m - 0.05f;                       // m - mu_10
    const float p = fast_exp2(-72.13475204f * x * x);
    S[10] += p;
    float u = fast_exp2(fmaf(m, 14.4269504089f, -1.44269504089f)); // exp(10m-1)
    float q = p;
    #pragma unroll
    for (int k = 11; k <= 19; ++k) {
        q *= u;
        S[k] += q;
        u *= 0.36787944117f;                         // e^-1
    }
    float v = fast_exp2(m * -14.4269504089f);        // exp(-10m)
    q = p;
    #pragma unroll
    for (int k = 9; k >= 0; --k) {
        q *= v;
        S[k] += q;
        v *= 0.36787944117f;
    }
    const float d = m - 1.0f;
    S[20] += fast_exp2(-721347.5204f * d * d);       // exact kernel, sigma=1e-3
}

// One block per batch item, BOTH preds fused: waves {0,1}->pred0, {2,3}->pred1.
// Grid = 1024 = 4 blocks/CU fully resident. Software-pipelined tile loop:
// loads for tile t+1 are issued between tile t's MFMA and its RBF ladder,
// so the ~700-cycle RBF phase hides the scattered-gather latency.
__global__ __launch_bounds__(256, 2) void knrm_main(
    const int* __restrict__ q1, const int* __restrict__ d1,
    const int* __restrict__ q2, const int* __restrict__ d2,
    const float* __restrict__ emb,
    const float* __restrict__ W1, const float* __restrict__ b1,
    const float* __restrict__ W2, const float* __restrict__ b2,
    const float* __restrict__ W3, const float* __restrict__ b3,
    float* __restrict__ out)        // [NB]
{
    __shared__ float sPhiW[4][LQ][NK];   // per-wave partial sums, 6.72 KB
    __shared__ float sX[2][NK];
    __shared__ float sH1[2][10];
    __shared__ float sH2[2][5];

    const int b    = blockIdx.x;
    const int t    = threadIdx.x;
    const int lane = t & 63, wave = t >> 6;
    const int pred = wave >> 1, wv = wave & 1;   // wv: which half of the tiles
    const int c    = lane & 15, quad = lane >> 4;
    const int* __restrict__ qi = pred ? q2 : q1;
    const int* __restrict__ di = pred ? d2 : d1;
    const float4* emb4 = (const float4*)emb;

    // ---- ids: q rows + rolling d-id prefetch (depth 1 tile ahead) ----
    const int qid0 = qi[b * LQ + c];                       // c < 16 < 20: no clamp
    const int r1   = 16 + c;
    const int qid1 = qi[b * LQ + (r1 < LQ ? r1 : LQ - 1)];
    int tile = wv;
    const int j0 = tile * 16 + c;
    const int id0 = di[b * LD + (j0 < LD ? j0 : LD - 1)];  // tile < 2 => j0 < LD
    int idn;
    {
        const int jn = j0 + 32;
        idn = di[b * LD + (jn < LD ? jn : LD - 1)];        // tile+2 <= 3 < NTILE
    }

    // ---- prologue: issue D-tile-0 loads (independent of Q conversion) ----
    float4 ld0, ld1, ld2, ld3, ld4, ld5, ld6, ld7;
    {
        const float4* db = emb4 + (size_t)(unsigned)id0 * E4;
        ld0 = db[quad * 2];      ld1 = db[quad * 2 + 1];
        ld2 = db[8 + quad * 2];  ld3 = db[8 + quad * 2 + 1];
        ld4 = db[16 + quad * 2]; ld5 = db[16 + quad * 2 + 1];
        ld6 = db[24 + quad * 2]; ld7 = db[24 + quad * 2 + 1];
    }

    // ---- Q fragments (B operand): cols i = c (Mt0) / 16+c (Mt1) ----
    bf16x8 aF[2][4];
    float rqA, rqB;
    {
        const float4* qb0 = emb4 + (size_t)(unsigned)qid0 * E4;
        const float4* qb1 = emb4 + (size_t)(unsigned)qid1 * E4;
        float qs0 = 0.f, qs1 = 0.f;
        #pragma unroll
        for (int ks = 0; ks < 4; ++ks) {
            float4 f0 = qb0[ks * 8 + quad * 2];
            float4 f1 = qb0[ks * 8 + quad * 2 + 1];
            qs0 = sq8(f0, f1, qs0);
            aF[0][ks] = pack8(f0, f1);
            float4 g0 = qb1[ks * 8 + quad * 2];
            float4 g1 = qb1[ks * 8 + quad * 2 + 1];
            qs1 = sq8(g0, g1, qs1);
            aF[1][ks] = pack8(g0, g1);
        }
        if (c >= LQ - 16) {                      // pad q-rows 20..31 -> exact zeros
            #pragma unroll
            for (int ks = 0; ks < 4; ++ks) aF[1][ks] = (bf16x8)0;
            qs1 = 0.f;
        }
        qs0 += __shfl_xor(qs0, 16); qs0 += __shfl_xor(qs0, 32);
        qs1 += __shfl_xor(qs1, 16); qs1 += __shfl_xor(qs1, 32);
        rqA = rsqrtf(qs0 + 1e-6f);
        rqB = rsqrtf(qs1 + 1e-6f);
    }

    // ---- per-lane RBF accumulators ----
    float S0[NK], S1[NK];
    #pragma unroll
    for (int k = 0; k < NK; ++k) { S0[k] = 0.f; S1[k] = 0.f; }

    #pragma unroll 1
    while (true) {
        // pad handling: only tile 12 (wv==0) has rows >= LD; zero them so m==0
        if (tile == NTILE - 1 && c >= (LD - (NTILE - 1) * 16)) {
            ld0 = ld1 = ld2 = ld3 = ld4 = ld5 = ld6 = ld7 = make_float4(0.f, 0.f, 0.f, 0.f);
        }

        // ---- convert-and-consume per k-step (bF transient: 4 VGPRs) ----
        float dsq = 0.f;
        f32x4 acc0 = {0.f, 0.f, 0.f, 0.f};
        f32x4 acc1 = {0.f, 0.f, 0.f, 0.f};
        {
            dsq = sq8(ld0, ld1, dsq);
            bf16x8 bFk = pack8(ld0, ld1);
            acc0 = __builtin_amdgcn_mfma_f32_16x16x32_bf16(bFk, aF[0][0], acc0, 0, 0, 0);
            acc1 = __builtin_amdgcn_mfma_f32_16x16x32_bf16(bFk, aF[1][0], acc1, 0, 0, 0);
        }
        {
            dsq = sq8(ld2, ld3, dsq);
            bf16x8 bFk = pack8(ld2, ld3);
            acc0 = __builtin_amdgcn_mfma_f32_16x16x32_bf16(bFk, aF[0][1], acc0, 0, 0, 0);
            acc1 = __builtin_amdgcn_mfma_f32_16x16x32_bf16(bFk, aF[1][1], acc1, 0, 0, 0);
        }
        {
            dsq = sq8(ld4, ld5, dsq);
            bf16x8 bFk = pack8(ld4, ld5);
            acc0 = __builtin_amdgcn_mfma_f32_16x16x32_bf16(bFk, aF[0][2], acc0, 0, 0, 0);
            acc1 = __builtin_amdgcn_mfma_f32_16x16x32_bf16(bFk, aF[1][2], acc1, 0, 0, 0);
        }
        {
            dsq = sq8(ld6, ld7, dsq);
            bf16x8 bFk = pack8(ld6, ld7);
            acc0 = __builtin_amdgcn_mfma_f32_16x16x32_bf16(bFk, aF[0][3], acc0, 0, 0, 0);
            acc1 = __builtin_amdgcn_mfma_f32_16x16x32_bf16(bFk, aF[1][3], acc1, 0, 0, 0);
        }

        // ---- issue NEXT tile's gathers now; RBF below hides their latency ----
        const int ntile = tile + 2;
        if (ntile < NTILE) {
            const float4* db = emb4 + (size_t)(unsigned)idn * E4;
            ld0 = db[quad * 2];      ld1 = db[quad * 2 + 1];
            ld2 = db[8 + quad * 2];  ld3 = db[8 + quad * 2 + 1];
            ld4 = db[16 + quad * 2]; ld5 = db[16 + quad * 2 + 1];
            ld6 = db[24 + quad * 2]; ld7 = db[24 + quad * 2 + 1];
            if (ntile + 2 < NTILE) {             // roll the id prefetch
                const int jn2 = (ntile + 2) * 16 + c;
                idn = di[b * LD + (jn2 < LD ? jn2 : LD - 1)];
            }
        }

        // ---- norms for current tile ----
        dsq += __shfl_xor(dsq, 16);
        dsq += __shfl_xor(dsq, 32);
        const float rdc = rsqrtf(dsq + 1e-6f);   // rd for d-row tile*16+c
        float rdv[4];
        #pragma unroll
        for (int r = 0; r < 4; ++r) rdv[r] = __shfl(rdc, quad * 4 + r);

        // acc0: i = c real for all lanes; 4 ladders per lane
        #pragma unroll
        for (int r = 0; r < 4; ++r)
            rbf_accum(acc0[r] * rdv[r] * rqA, S0);

        // acc1: only cols c<4 real (i=16..19); redistribute -> 1 ladder per lane
        float m1[4];
        #pragma unroll
        for (int r = 0; r < 4; ++r) m1[r] = acc1[r] * rdv[r] * rqB;
        const int src = (lane & 48) | ((lane >> 2) & 3);
        const float g0 = __shfl(m1[0], src);
        const float g1 = __shfl(m1[1], src);
        const float g2 = __shfl(m1[2], src);
        const float g3 = __shfl(m1[3], src);
        const int rsel = lane & 3;
        const float mv = (rsel == 0) ? g0 : (rsel == 1) ? g1 : (rsel == 2) ? g2 : g3;
        rbf_accum(mv, S1);

        tile += 2;
        if (tile >= NTILE) break;
    }

    // ---- reductions ----
    #pragma unroll
    for (int k = 0; k < NK; ++k) {
        S0[k] += __shfl_xor(S0[k], 16);
        S0[k] += __shfl_xor(S0[k], 32);
        S1[k] += __shfl_xor(S1[k], 1);
        S1[k] += __shfl_xor(S1[k], 2);
        S1[k] += __shfl_xor(S1[k], 16);
        S1[k] += __shfl_xor(S1[k], 32);
    }
    if (quad == 0) {
        #pragma unroll
        for (int k = 0; k < NK; ++k) sPhiW[wave][c][k] = S0[k];
    }
    if ((lane & 51) == 0) {                       // lanes 0,4,8,12 -> i = 16..19
        #pragma unroll
        for (int k = 0; k < NK; ++k) sPhiW[wave][16 + (lane >> 2)][k] = S1[k];
    }
    __syncthreads();

    // ---- epilogue: waves 0/1 handle pred 0/1 in parallel ----
    const int ew = t >> 6, et = t & 63;

    // log1p + sum over i; subtract the 8 padded-j rows (each added phi_k(0))
    if (ew < 2 && et < NK) {
        const float mu_t = 0.1f * (float)et - 0.95f;
        const float pad  = (et < 20) ? 8.0f * fast_exp2(-72.13475204f * mu_t * mu_t) : 0.0f;
        float s = 0.f;
        #pragma unroll
        for (int i = 0; i < LQ; ++i) {
            const float v = sPhiW[2 * ew][i][et] + sPhiW[2 * ew + 1][i][et] - pad;
            s += __logf(1.0f + v);
        }
        sX[ew][et] = fmaxf(s, 0.f);   // relu (guards tiny negative from pad cancel)
    }
    __syncthreads();

    if (ew < 2 && et < 10) {
        float v = b1[et];
        #pragma unroll
        for (int k = 0; k < NK; ++k) v += W1[et * NK + k] * sX[ew][k];
        sH1[ew][et] = fmaxf(v, 0.f);
    }
    __syncthreads();

    if (ew < 2 && et < 5) {
        float v = b2[et];
        #pragma unroll
        for (int k = 0; k < 10; ++k) v += W2[et * 10 + k] * sH1[ew][k];
        sH2[ew][et] = fmaxf(v, 0.f);
    }
    __syncthreads();

    if (t == 0) {
        float l0 = b3[0], l1 = b3[0];
        #pragma unroll
        for (int k = 0; k < 5; ++k) {
            l0 += W3[k] * sH2[0][k];
            l1 += W3[k] * sH2[1][k];
        }
        out[b] = 1.0f / (1.0f + __expf(l1 - l0));   // sigmoid(l0 - l1)
    }
}

extern "C" void kernel_launch(void* const* d_in, const int* in_sizes, int n_in,
                              void* d_out, int out_size, void* d_ws, size_t ws_size,
                              hipStream_t stream) {
    knrm_main<<<NB, 256, 0, stream>>>(
        (const int*)d_in[0], (const int*)d_in[1],
        (const int*)d_in[2], (const int*)d_in[3],
        (const float*)d_in[4],
        (const float*)d_in[5], (const float*)d_in[6],
        (const float*)d_in[7], (const float*)d_in[8],
        (const float*)d_in[9], (const float*)d_in[10],
        (float*)d_out);
}

// Round 8
// 137.120 us; speedup vs baseline: 1.5844x; 1.0044x over previous
//
#include <hip/hip_runtime.h>
#include <hip/hip_bf16.h>

#define NB 1024
#define LQ 20
#define LD 200
#define E4 32      // 128 floats / 4
#define NK 21
#define NTILE 13   // ceil(208/16) j-tiles of 16 d-cols

typedef __attribute__((ext_vector_type(8))) short bf16x8;   // 8 bf16 = 4 VGPRs
typedef __attribute__((ext_vector_type(4))) float f32x4;
typedef __attribute__((ext_vector_type(2))) float f32x2;    // v_pk_*_f32 target

// Packed f32->bf16 RNE via the cast path (compiler emits v_cvt_pk_bf16_f32).
__device__ __forceinline__ unsigned cvt2(float lo, float hi) {
    __hip_bfloat162 h = __float22bfloat162_rn(make_float2(lo, hi));
    unsigned u;
    __builtin_memcpy(&u, &h, 4);
    return u;
}

__device__ __forceinline__ bf16x8 pack8(float4 f0, float4 f1) {
    union { unsigned u[4]; bf16x8 v; } r;
    r.u[0] = cvt2(f0.x, f0.y);
    r.u[1] = cvt2(f0.z, f0.w);
    r.u[2] = cvt2(f1.x, f1.y);
    r.u[3] = cvt2(f1.z, f1.w);
    return r.v;
}

// Norm accumulation from RAW f32 (matches reference norms).
__device__ __forceinline__ float sq8(float4 f0, float4 f1, float s) {
    s = fmaf(f0.x, f0.x, s); s = fmaf(f0.y, f0.y, s);
    s = fmaf(f0.z, f0.z, s); s = fmaf(f0.w, f0.w, s);
    s = fmaf(f1.x, f1.x, s); s = fmaf(f1.y, f1.y, s);
    s = fmaf(f1.z, f1.z, s); s = fmaf(f1.w, f1.w, s);
    return s;
}

__device__ __forceinline__ float fast_exp2(float x) {
#if __has_builtin(__builtin_amdgcn_exp2f)
    return __builtin_amdgcn_exp2f(x);
#else
    return __expf(x * 0.69314718056f);
#endif
}

// phi_{10+-n}(m) = p * w^n * D_n  with  x = m-0.05, p = e^{-50x^2},
// w = e^{+-10x}, D_n = e^{-n^2/2} (constant table). 2 insts per kernel-eval
// (mul + fma) vs 3 in the decaying-ratio form. k=20 exact (sigma=1e-3).
#define DN0 0.60653066f
#define DN1 0.13533528f
#define DN2 1.1108997e-2f
#define DN3 3.3546263e-4f
#define DN4 3.7266532e-6f
#define DN5 1.5229979e-8f
#define DN6 2.2897348e-11f
#define DN7 1.2664166e-14f
#define DN8 2.5767912e-18f
#define DN9 1.9287498e-22f

__device__ __forceinline__ f32x2 pk_exp2(f32x2 a) {
    f32x2 r; r.x = fast_exp2(a.x); r.y = fast_exp2(a.y); return r;
}

// Packed ladder: two m-values per pass (v_pk_mul_f32 / v_pk_fma_f32).
__device__ __forceinline__ void rbf2(f32x2 m, f32x2* S) {
    const float DN[10] = {DN0, DN1, DN2, DN3, DN4, DN5, DN6, DN7, DN8, DN9};
    const f32x2 x = m - 0.05f;
    const f32x2 p = pk_exp2(x * x * -72.13475204f);
    S[10] += p;
    f32x2 w = pk_exp2(x * 14.4269504089f);           // e^{10x}
    f32x2 q = p;
    #pragma unroll
    for (int n = 1; n <= 9; ++n) {
        q = q * w;
        S[10 + n] = __builtin_elementwise_fma(q, (f32x2)(DN[n - 1]), S[10 + n]);
    }
    w = pk_exp2(x * -14.4269504089f);                // e^{-10x}
    q = p;
    #pragma unroll
    for (int n = 1; n <= 10; ++n) {
        q = q * w;
        S[10 - n] = __builtin_elementwise_fma(q, (f32x2)(DN[n - 1]), S[10 - n]);
    }
    const f32x2 d = m - 1.0f;
    S[20] += pk_exp2(d * d * -721347.5204f);         // exact kernel
}

// Scalar ladder (same algebra) for the S1 value.
__device__ __forceinline__ void rbf1(float m, float* S) {
    const float DN[10] = {DN0, DN1, DN2, DN3, DN4, DN5, DN6, DN7, DN8, DN9};
    const float x = m - 0.05f;
    const float p = fast_exp2(x * x * -72.13475204f);
    S[10] += p;
    float w = fast_exp2(x * 14.4269504089f);
    float q = p;
    #pragma unroll
    for (int n = 1; n <= 9; ++n) {
        q *= w;
        S[10 + n] = fmaf(q, DN[n - 1], S[10 + n]);
    }
    w = fast_exp2(x * -14.4269504089f);
    q = p;
    #pragma unroll
    for (int n = 1; n <= 10; ++n) {
        q *= w;
        S[10 - n] = fmaf(q, DN[n - 1], S[10 - n]);
    }
    const float d = m - 1.0f;
    S[20] += fast_exp2(d * d * -721347.5204f);
}

// One block per batch item, BOTH preds fused: waves {0,1}->pred0, {2,3}->pred1.
// Grid = 1024 = 4 blocks/CU fully resident. Software-pipelined tile loop:
// loads for tile t+1 issued between tile t's MFMA and its RBF ladders.
__global__ __launch_bounds__(256, 2) void knrm_main(
    const int* __restrict__ q1, const int* __restrict__ d1,
    const int* __restrict__ q2, const int* __restrict__ d2,
    const float* __restrict__ emb,
    const float* __restrict__ W1, const float* __restrict__ b1,
    const float* __restrict__ W2, const float* __restrict__ b2,
    const float* __restrict__ W3, const float* __restrict__ b3,
    float* __restrict__ out)        // [NB]
{
    __shared__ float sPhiW[4][LQ][NK];   // per-wave partial sums, 6.72 KB
    __shared__ float sX[2][NK];
    __shared__ float sH1[2][10];
    __shared__ float sH2[2][5];

    const int b    = blockIdx.x;
    const int t    = threadIdx.x;
    const int lane = t & 63, wave = t >> 6;
    const int pred = wave >> 1, wv = wave & 1;   // wv: which half of the tiles
    const int c    = lane & 15, quad = lane >> 4;
    const int* __restrict__ qi = pred ? q2 : q1;
    const int* __restrict__ di = pred ? d2 : d1;
    const float4* emb4 = (const float4*)emb;

    // ---- ids: q rows + rolling d-id prefetch (depth 1 tile ahead) ----
    const int qid0 = qi[b * LQ + c];                       // c < 16 < 20: no clamp
    const int r1   = 16 + c;
    const int qid1 = qi[b * LQ + (r1 < LQ ? r1 : LQ - 1)];
    int tile = wv;
    const int j0 = tile * 16 + c;
    const int id0 = di[b * LD + (j0 < LD ? j0 : LD - 1)];
    int idn;
    {
        const int jn = j0 + 32;
        idn = di[b * LD + (jn < LD ? jn : LD - 1)];
    }

    // ---- prologue: issue D-tile-0 loads ----
    float4 ld0, ld1, ld2, ld3, ld4, ld5, ld6, ld7;
    {
        const float4* db = emb4 + (size_t)(unsigned)id0 * E4;
        ld0 = db[quad * 2];      ld1 = db[quad * 2 + 1];
        ld2 = db[8 + quad * 2];  ld3 = db[8 + quad * 2 + 1];
        ld4 = db[16 + quad * 2]; ld5 = db[16 + quad * 2 + 1];
        ld6 = db[24 + quad * 2]; ld7 = db[24 + quad * 2 + 1];
    }

    // ---- Q fragments (B operand): cols i = c (Mt0) / 16+c (Mt1) ----
    bf16x8 aF[2][4];
    float rqA, rqB;
    {
        const float4* qb0 = emb4 + (size_t)(unsigned)qid0 * E4;
        const float4* qb1 = emb4 + (size_t)(unsigned)qid1 * E4;
        float qs0 = 0.f, qs1 = 0.f;
        #pragma unroll
        for (int ks = 0; ks < 4; ++ks) {
            float4 f0 = qb0[ks * 8 + quad * 2];
            float4 f1 = qb0[ks * 8 + quad * 2 + 1];
            qs0 = sq8(f0, f1, qs0);
            aF[0][ks] = pack8(f0, f1);
            float4 g0 = qb1[ks * 8 + quad * 2];
            float4 g1 = qb1[ks * 8 + quad * 2 + 1];
            qs1 = sq8(g0, g1, qs1);
            aF[1][ks] = pack8(g0, g1);
        }
        if (c >= LQ - 16) {                      // pad q-rows 20..31 -> exact zeros
            #pragma unroll
            for (int ks = 0; ks < 4; ++ks) aF[1][ks] = (bf16x8)0;
            qs1 = 0.f;
        }
        qs0 += __shfl_xor(qs0, 16); qs0 += __shfl_xor(qs0, 32);
        qs1 += __shfl_xor(qs1, 16); qs1 += __shfl_xor(qs1, 32);
        rqA = rsqrtf(qs0 + 1e-6f);
        rqB = rsqrtf(qs1 + 1e-6f);
    }

    // ---- per-lane RBF accumulators ----
    // Sp (packed): pass1 (.x=r0,.y=r1), pass2 (.x=r2,.y=r3); S0 = .x+.y at fold.
    // S1 (scalar): redistributed value, i = 16+((lane>>2)&3).
    f32x2 Sp[NK];
    float S1[NK];
    #pragma unroll
    for (int k = 0; k < NK; ++k) { Sp[k] = (f32x2)(0.f); S1[k] = 0.f; }

    #pragma unroll 1
    while (true) {
        // pad handling: only tile 12 (wv==0) has rows >= LD; zero them so m==0
        if (tile == NTILE - 1 && c >= (LD - (NTILE - 1) * 16)) {
            ld0 = ld1 = ld2 = ld3 = ld4 = ld5 = ld6 = ld7 = make_float4(0.f, 0.f, 0.f, 0.f);
        }

        // ---- convert-and-consume per k-step (bF transient: 4 VGPRs) ----
        float dsq = 0.f;
        f32x4 acc0 = {0.f, 0.f, 0.f, 0.f};
        f32x4 acc1 = {0.f, 0.f, 0.f, 0.f};
        {
            dsq = sq8(ld0, ld1, dsq);
            bf16x8 bFk = pack8(ld0, ld1);
            acc0 = __builtin_amdgcn_mfma_f32_16x16x32_bf16(bFk, aF[0][0], acc0, 0, 0, 0);
            acc1 = __builtin_amdgcn_mfma_f32_16x16x32_bf16(bFk, aF[1][0], acc1, 0, 0, 0);
        }
        {
            dsq = sq8(ld2, ld3, dsq);
            bf16x8 bFk = pack8(ld2, ld3);
            acc0 = __builtin_amdgcn_mfma_f32_16x16x32_bf16(bFk, aF[0][1], acc0, 0, 0, 0);
            acc1 = __builtin_amdgcn_mfma_f32_16x16x32_bf16(bFk, aF[1][1], acc1, 0, 0, 0);
        }
        {
            dsq = sq8(ld4, ld5, dsq);
            bf16x8 bFk = pack8(ld4, ld5);
            acc0 = __builtin_amdgcn_mfma_f32_16x16x32_bf16(bFk, aF[0][2], acc0, 0, 0, 0);
            acc1 = __builtin_amdgcn_mfma_f32_16x16x32_bf16(bFk, aF[1][2], acc1, 0, 0, 0);
        }
        {
            dsq = sq8(ld6, ld7, dsq);
            bf16x8 bFk = pack8(ld6, ld7);
            acc0 = __builtin_amdgcn_mfma_f32_16x16x32_bf16(bFk, aF[0][3], acc0, 0, 0, 0);
            acc1 = __builtin_amdgcn_mfma_f32_16x16x32_bf16(bFk, aF[1][3], acc1, 0, 0, 0);
        }

        // ---- issue NEXT tile's gathers; RBF below hides their latency ----
        const int ntile = tile + 2;
        if (ntile < NTILE) {
            const float4* db = emb4 + (size_t)(unsigned)idn * E4;
            ld0 = db[quad * 2];      ld1 = db[quad * 2 + 1];
            ld2 = db[8 + quad * 2];  ld3 = db[8 + quad * 2 + 1];
            ld4 = db[16 + quad * 2]; ld5 = db[16 + quad * 2 + 1];
            ld6 = db[24 + quad * 2]; ld7 = db[24 + quad * 2 + 1];
            if (ntile + 2 < NTILE) {             // roll the id prefetch
                const int jn2 = (ntile + 2) * 16 + c;
                idn = di[b * LD + (jn2 < LD ? jn2 : LD - 1)];
            }
        }

        // ---- norms for current tile ----
        dsq += __shfl_xor(dsq, 16);
        dsq += __shfl_xor(dsq, 32);
        const float rdc = rsqrtf(dsq + 1e-6f);   // rd for d-row tile*16+c
        float rdv[4];
        #pragma unroll
        for (int r = 0; r < 4; ++r) rdv[r] = __shfl(rdc, quad * 4 + r);

        // acc0: i = c real for all lanes; 2 packed ladders (4 m-values)
        f32x2 ma, mb;
        ma.x = acc0[0] * rdv[0] * rqA;
        ma.y = acc0[1] * rdv[1] * rqA;
        mb.x = acc0[2] * rdv[2] * rqA;
        mb.y = acc0[3] * rdv[3] * rqA;
        rbf2(ma, Sp);
        rbf2(mb, Sp);

        // acc1: only cols c<4 real (i=16..19); redistribute -> 1 scalar ladder
        float m1[4];
        #pragma unroll
        for (int r = 0; r < 4; ++r) m1[r] = acc1[r] * rdv[r] * rqB;
        const int src = (lane & 48) | ((lane >> 2) & 3);
        const float g0 = __shfl(m1[0], src);
        const float g1 = __shfl(m1[1], src);
        const float g2 = __shfl(m1[2], src);
        const float g3 = __shfl(m1[3], src);
        const int rsel = lane & 3;
        const float mv = (rsel == 0) ? g0 : (rsel == 1) ? g1 : (rsel == 2) ? g2 : g3;
        rbf1(mv, S1);

        tile += 2;
        if (tile >= NTILE) break;
    }

    // ---- reductions ----
    float S0f[NK];
    #pragma unroll
    for (int k = 0; k < NK; ++k) {
        float s0 = Sp[k].x + Sp[k].y;
        s0 += __shfl_xor(s0, 16);
        s0 += __shfl_xor(s0, 32);
        S0f[k] = s0;
        S1[k] += __shfl_xor(S1[k], 1);
        S1[k] += __shfl_xor(S1[k], 2);
        S1[k] += __shfl_xor(S1[k], 16);
        S1[k] += __shfl_xor(S1[k], 32);
    }
    if (quad == 0) {
        #pragma unroll
        for (int k = 0; k < NK; ++k) sPhiW[wave][c][k] = S0f[k];
    }
    if ((lane & 51) == 0) {                       // lanes 0,4,8,12 -> i = 16..19
        #pragma unroll
        for (int k = 0; k < NK; ++k) sPhiW[wave][16 + (lane >> 2)][k] = S1[k];
    }
    __syncthreads();

    // ---- epilogue: waves 0/1 handle pred 0/1 in parallel ----
    const int ew = t >> 6, et = t & 63;

    // log1p + sum over i; subtract the 8 padded-j rows (each added phi_k(0))
    if (ew < 2 && et < NK) {
        const float mu_t = 0.1f * (float)et - 0.95f;
        const float pad  = (et < 20) ? 8.0f * fast_exp2(-72.13475204f * mu_t * mu_t) : 0.0f;
        float s = 0.f;
        #pragma unroll
        for (int i = 0; i < LQ; ++i) {
            const float v = sPhiW[2 * ew][i][et] + sPhiW[2 * ew + 1][i][et] - pad;
            s += __logf(1.0f + v);
        }
        sX[ew][et] = fmaxf(s, 0.f);   // relu (guards tiny negative from pad cancel)
    }
    __syncthreads();

    if (ew < 2 && et < 10) {
        float v = b1[et];
        #pragma unroll
        for (int k = 0; k < NK; ++k) v += W1[et * NK + k] * sX[ew][k];
        sH1[ew][et] = fmaxf(v, 0.f);
    }
    __syncthreads();

    if (ew < 2 && et < 5) {
        float v = b2[et];
        #pragma unroll
        for (int k = 0; k < 10; ++k) v += W2[et * 10 + k] * sH1[ew][k];
        sH2[ew][et] = fmaxf(v, 0.f);
    }
    __syncthreads();

    if (t == 0) {
        float l0 = b3[0], l1 = b3[0];
        #pragma unroll
        for (int k = 0; k < 5; ++k) {
            l0 += W3[k] * sH2[0][k];
            l1 += W3[k] * sH2[1][k];
        }
        out[b] = 1.0f / (1.0f + __expf(l1 - l0));   // sigmoid(l0 - l1)
    }
}

extern "C" void kernel_launch(void* const* d_in, const int* in_sizes, int n_in,
                              void* d_out, int out_size, void* d_ws, size_t ws_size,
                              hipStream_t stream) {
    knrm_main<<<NB, 256, 0, stream>>>(
        (const int*)d_in[0], (const int*)d_in[1],
        (const int*)d_in[2], (const int*)d_in[3],
        (const float*)d_in[4],
        (const float*)d_in[5], (const float*)d_in[6],
        (const float*)d_in[7], (const float*)d_in[8],
        (const float*)d_in[9], (const float*)d_in[10],
        (float*)d_out);
}

// Round 9
// 132.939 us; speedup vs baseline: 1.6342x; 1.0315x over previous
//
#include <hip/hip_runtime.h>
#include <hip/hip_bf16.h>

#define NB 1024
#define LQ 20
#define LD 200
#define E4 32      // 128 floats / 4
#define NK 21
#define NTILE 13   // ceil(208/16) j-tiles of 16 d-cols
#define MDUMMY 3.0f   // ladder input whose every contribution underflows to exact 0

typedef __attribute__((ext_vector_type(8))) short bf16x8;   // 8 bf16 = 4 VGPRs
typedef __attribute__((ext_vector_type(4))) float f32x4;
typedef __attribute__((ext_vector_type(2))) float f32x2;    // v_pk_*_f32 target

// Packed f32->bf16 RNE via the cast path (compiler emits v_cvt_pk_bf16_f32).
__device__ __forceinline__ unsigned cvt2(float lo, float hi) {
    __hip_bfloat162 h = __float22bfloat162_rn(make_float2(lo, hi));
    unsigned u;
    __builtin_memcpy(&u, &h, 4);
    return u;
}

__device__ __forceinline__ bf16x8 pack8(float4 f0, float4 f1) {
    union { unsigned u[4]; bf16x8 v; } r;
    r.u[0] = cvt2(f0.x, f0.y);
    r.u[1] = cvt2(f0.z, f0.w);
    r.u[2] = cvt2(f1.x, f1.y);
    r.u[3] = cvt2(f1.z, f1.w);
    return r.v;
}

__device__ __forceinline__ f32x2 fma2(f32x2 a, f32x2 b, f32x2 c) {
    return __builtin_elementwise_fma(a, b, c);
}

// Packed norm accumulation from RAW f32 (v_pk_fma_f32: 4 insts per 8 floats).
__device__ __forceinline__ f32x2 sqacc(float4 f0, float4 f1, f32x2 s) {
    f32x2 a = {f0.x, f0.y}, b = {f0.z, f0.w};
    f32x2 c = {f1.x, f1.y}, d = {f1.z, f1.w};
    s = fma2(a, a, s); s = fma2(b, b, s);
    s = fma2(c, c, s); s = fma2(d, d, s);
    return s;
}

__device__ __forceinline__ float fast_exp2(float x) {
#if __has_builtin(__builtin_amdgcn_exp2f)
    return __builtin_amdgcn_exp2f(x);
#else
    return __expf(x * 0.69314718056f);
#endif
}

// phi_{10+-n}(m) = p * w^n * D_n, x = m-0.05, p = e^{-50x^2}, w = e^{+-10x},
// D_n = e^{-n^2/2} constant. k=20 (exact kernel) handled by the CALLER:
// it underflows to exact 0.0f unless m > 0.98 (5e5*(m-1)^2 > 200 >> 87).
#define DN0 0.60653066f
#define DN1 0.13533528f
#define DN2 1.1108997e-2f
#define DN3 3.3546263e-4f
#define DN4 3.7266532e-6f
#define DN5 1.5229979e-8f
#define DN6 2.2897348e-11f
#define DN7 1.2664166e-14f
#define DN8 2.5767912e-18f
#define DN9 1.9287498e-22f

__device__ __forceinline__ f32x2 pk_exp2(f32x2 a) {
    f32x2 r; r.x = fast_exp2(a.x); r.y = fast_exp2(a.y); return r;
}

// Packed Gaussian ladder for k=0..19 (two m-values per pass).
// For m = MDUMMY: p = exp2(-627) = 0 exactly -> all contributions exactly 0.
__device__ __forceinline__ void rbf2(f32x2 m, f32x2* S) {
    const float DN[10] = {DN0, DN1, DN2, DN3, DN4, DN5, DN6, DN7, DN8, DN9};
    const f32x2 x = m - 0.05f;
    const f32x2 p = pk_exp2(x * x * -72.13475204f);
    S[10] += p;
    f32x2 w = pk_exp2(x * 14.4269504089f);           // e^{10x}
    f32x2 q = p;
    #pragma unroll
    for (int n = 1; n <= 9; ++n) {
        q = q * w;
        S[10 + n] = fma2(q, (f32x2)(DN[n - 1]), S[10 + n]);
    }
    w = pk_exp2(x * -14.4269504089f);                // e^{-10x}
    q = p;
    #pragma unroll
    for (int n = 1; n <= 10; ++n) {
        q = q * w;
        S[10 - n] = fma2(q, (f32x2)(DN[n - 1]), S[10 - n]);
    }
}

// One block per batch item, BOTH preds fused: waves {0,1}->pred0, {2,3}->pred1.
// Grid = 1024 = 4 blocks/CU fully resident. Software-pipelined unrolled tile
// loop; acc1's ladder values are buffered (static indices) and run packed at
// the end; exact kernel (k=20) behind a wave-uniform rarely-taken branch.
__global__ __launch_bounds__(256, 2) void knrm_main(
    const int* __restrict__ q1, const int* __restrict__ d1,
    const int* __restrict__ q2, const int* __restrict__ d2,
    const float* __restrict__ emb,
    const float* __restrict__ W1, const float* __restrict__ b1,
    const float* __restrict__ W2, const float* __restrict__ b2,
    const float* __restrict__ W3, const float* __restrict__ b3,
    float* __restrict__ out)        // [NB]
{
    __shared__ float sPhiW[4][LQ][NK];   // per-wave partial sums, 6.72 KB
    __shared__ float sX[2][NK];
    __shared__ float sH1[2][10];
    __shared__ float sH2[2][5];

    const int b    = blockIdx.x;
    const int t    = threadIdx.x;
    const int lane = t & 63, wave = t >> 6;
    const int pred = wave >> 1, wv = wave & 1;   // wv: which half of the tiles
    const int c    = lane & 15, quad = lane >> 4;
    const int* __restrict__ qi = pred ? q2 : q1;
    const int* __restrict__ di = pred ? d2 : d1;
    const float4* emb4 = (const float4*)emb;

    // ---- ids: q rows + rolling d-id prefetch (depth 1 tile ahead) ----
    const int qid0 = qi[b * LQ + c];
    const int r1   = 16 + c;
    const int qid1 = qi[b * LQ + (r1 < LQ ? r1 : LQ - 1)];
    const int j0   = wv * 16 + c;
    const int id0  = di[b * LD + j0];                      // j0 <= 31 < 200
    int idn = di[b * LD + j0 + 32];                        // j0+32 <= 63 < 200

    // ---- prologue: issue D-tile-0 loads ----
    float4 ld0, ld1, ld2, ld3, ld4, ld5, ld6, ld7;
    {
        const float4* db = emb4 + (size_t)(unsigned)id0 * E4;
        ld0 = db[quad * 2];      ld1 = db[quad * 2 + 1];
        ld2 = db[8 + quad * 2];  ld3 = db[8 + quad * 2 + 1];
        ld4 = db[16 + quad * 2]; ld5 = db[16 + quad * 2 + 1];
        ld6 = db[24 + quad * 2]; ld7 = db[24 + quad * 2 + 1];
    }

    // ---- Q fragments (B operand): cols i = c (Mt0) / 16+c (Mt1) ----
    bf16x8 aF[2][4];
    float rqA, rqB;
    {
        const float4* qb0 = emb4 + (size_t)(unsigned)qid0 * E4;
        const float4* qb1 = emb4 + (size_t)(unsigned)qid1 * E4;
        f32x2 q0 = {0.f, 0.f}, q1v = {0.f, 0.f};
        #pragma unroll
        for (int ks = 0; ks < 4; ++ks) {
            float4 f0 = qb0[ks * 8 + quad * 2];
            float4 f1 = qb0[ks * 8 + quad * 2 + 1];
            q0 = sqacc(f0, f1, q0);
            aF[0][ks] = pack8(f0, f1);
            float4 g0 = qb1[ks * 8 + quad * 2];
            float4 g1 = qb1[ks * 8 + quad * 2 + 1];
            q1v = sqacc(g0, g1, q1v);
            aF[1][ks] = pack8(g0, g1);
        }
        float qs0 = q0.x + q0.y, qs1 = q1v.x + q1v.y;
        if (c >= LQ - 16) {                      // pad q-rows 20..31 -> exact zeros
            #pragma unroll
            for (int ks = 0; ks < 4; ++ks) aF[1][ks] = (bf16x8)0;
            qs1 = 0.f;
        }
        qs0 += __shfl_xor(qs0, 16); qs0 += __shfl_xor(qs0, 32);
        qs1 += __shfl_xor(qs1, 16); qs1 += __shfl_xor(qs1, 32);
        rqA = rsqrtf(qs0 + 1e-6f);
        rqB = rsqrtf(qs1 + 1e-6f);
    }

    // ---- per-lane accumulators ----
    // Sp (packed, acc0 stream): S0 = .x+.y at fold.  mv[]: deferred acc1 values.
    f32x2 Sp[NK];
    #pragma unroll
    for (int k = 0; k < NK; ++k) Sp[k] = (f32x2)(0.f);
    float mv[8];
    mv[7] = MDUMMY;

    #pragma unroll
    for (int ti = 0; ti < 7; ++ti) {
        const int tile = wv + 2 * ti;            // wave-uniform
        if (tile < NTILE) {
            // pad: only tile 12 has rows >= LD; zero them so m == 0 exactly
            if (tile == NTILE - 1 && c >= (LD - (NTILE - 1) * 16)) {
                ld0 = ld1 = ld2 = ld3 = ld4 = ld5 = ld6 = ld7 =
                    make_float4(0.f, 0.f, 0.f, 0.f);
            }

            // ---- convert-and-consume per k-step (bF transient) ----
            f32x2 dq = {0.f, 0.f};
            f32x4 acc0 = {0.f, 0.f, 0.f, 0.f};
            f32x4 acc1 = {0.f, 0.f, 0.f, 0.f};
            {
                dq = sqacc(ld0, ld1, dq);
                bf16x8 bFk = pack8(ld0, ld1);
                acc0 = __builtin_amdgcn_mfma_f32_16x16x32_bf16(bFk, aF[0][0], acc0, 0, 0, 0);
                acc1 = __builtin_amdgcn_mfma_f32_16x16x32_bf16(bFk, aF[1][0], acc1, 0, 0, 0);
            }
            {
                dq = sqacc(ld2, ld3, dq);
                bf16x8 bFk = pack8(ld2, ld3);
                acc0 = __builtin_amdgcn_mfma_f32_16x16x32_bf16(bFk, aF[0][1], acc0, 0, 0, 0);
                acc1 = __builtin_amdgcn_mfma_f32_16x16x32_bf16(bFk, aF[1][1], acc1, 0, 0, 0);
            }
            {
                dq = sqacc(ld4, ld5, dq);
                bf16x8 bFk = pack8(ld4, ld5);
                acc0 = __builtin_amdgcn_mfma_f32_16x16x32_bf16(bFk, aF[0][2], acc0, 0, 0, 0);
                acc1 = __builtin_amdgcn_mfma_f32_16x16x32_bf16(bFk, aF[1][2], acc1, 0, 0, 0);
            }
            {
                dq = sqacc(ld6, ld7, dq);
                bf16x8 bFk = pack8(ld6, ld7);
                acc0 = __builtin_amdgcn_mfma_f32_16x16x32_bf16(bFk, aF[0][3], acc0, 0, 0, 0);
                acc1 = __builtin_amdgcn_mfma_f32_16x16x32_bf16(bFk, aF[1][3], acc1, 0, 0, 0);
            }

            // ---- issue NEXT tile's gathers; ladder below hides latency ----
            const int ntile = tile + 2;
            if (ntile < NTILE) {
                const float4* db = emb4 + (size_t)(unsigned)idn * E4;
                ld0 = db[quad * 2];      ld1 = db[quad * 2 + 1];
                ld2 = db[8 + quad * 2];  ld3 = db[8 + quad * 2 + 1];
                ld4 = db[16 + quad * 2]; ld5 = db[16 + quad * 2 + 1];
                ld6 = db[24 + quad * 2]; ld7 = db[24 + quad * 2 + 1];
                if (ntile + 2 < NTILE) {         // roll the id prefetch
                    const int jn2 = (ntile + 2) * 16 + c;
                    idn = di[b * LD + (jn2 < LD ? jn2 : LD - 1)];
                }
            }

            // ---- norms for current tile ----
            float dsq = dq.x + dq.y;
            dsq += __shfl_xor(dsq, 16);
            dsq += __shfl_xor(dsq, 32);
            const float rdc = rsqrtf(dsq + 1e-6f);
            float rdv[4];
            #pragma unroll
            for (int r = 0; r < 4; ++r) rdv[r] = __shfl(rdc, quad * 4 + r);

            // acc0: i = c real for all lanes; 2 packed ladders
            const f32x2 r01 = {rdv[0], rdv[1]}, r23 = {rdv[2], rdv[3]};
            f32x2 ma = {acc0[0], acc0[1]};
            f32x2 mb = {acc0[2], acc0[3]};
            ma = ma * r01 * rqA;
            mb = mb * r23 * rqA;
            rbf2(ma, Sp);
            rbf2(mb, Sp);

            // exact kernel (k=20): exact 0 unless some m > 0.98 (rare: id match)
            const float mx = fmaxf(fmaxf(ma.x, ma.y), fmaxf(mb.x, mb.y));
            if (__any(mx > 0.98f)) {
                const f32x2 da = ma - 1.0f, db2 = mb - 1.0f;
                Sp[20] += pk_exp2(da * da * -721347.5204f);
                Sp[20] += pk_exp2(db2 * db2 * -721347.5204f);
            }

            // acc1: only cols c<4 real (i=16..19); redistribute, DEFER ladder
            f32x2 n01 = {acc1[0], acc1[1]};
            f32x2 n23 = {acc1[2], acc1[3]};
            n01 = n01 * r01 * rqB;
            n23 = n23 * r23 * rqB;
            const int src = (lane & 48) | ((lane >> 2) & 3);
            const float g0 = __shfl(n01.x, src);
            const float g1 = __shfl(n01.y, src);
            const float g2 = __shfl(n23.x, src);
            const float g3 = __shfl(n23.y, src);
            const int rsel = lane & 3;
            mv[ti] = (rsel == 0) ? g0 : (rsel == 1) ? g1 : (rsel == 2) ? g2 : g3;
        } else {
            mv[ti] = MDUMMY;                     // wv==1, ti==6
        }
    }

    // ---- deferred acc1 ladders: 4 packed passes over the buffered values ----
    f32x2 S1p[NK];
    #pragma unroll
    for (int k = 0; k < NK; ++k) S1p[k] = (f32x2)(0.f);
    #pragma unroll
    for (int pp = 0; pp < 4; ++pp) {
        f32x2 mm;
        mm.x = mv[2 * pp];
        mm.y = mv[2 * pp + 1];
        rbf2(mm, S1p);
        const f32x2 dd = mm - 1.0f;
        S1p[20] += pk_exp2(dd * dd * -721347.5204f);
    }

    // ---- reductions ----
    float S0f[NK], S1f[NK];
    #pragma unroll
    for (int k = 0; k < NK; ++k) {
        float s0 = Sp[k].x + Sp[k].y;
        s0 += __shfl_xor(s0, 16);
        s0 += __shfl_xor(s0, 32);
        S0f[k] = s0;
        float s1 = S1p[k].x + S1p[k].y;
        s1 += __shfl_xor(s1, 1);
        s1 += __shfl_xor(s1, 2);
        s1 += __shfl_xor(s1, 16);
        s1 += __shfl_xor(s1, 32);
        S1f[k] = s1;
    }
    if (quad == 0) {
        #pragma unroll
        for (int k = 0; k < NK; ++k) sPhiW[wave][c][k] = S0f[k];
    }
    if ((lane & 51) == 0) {                       // lanes 0,4,8,12 -> i = 16..19
        #pragma unroll
        for (int k = 0; k < NK; ++k) sPhiW[wave][16 + (lane >> 2)][k] = S1f[k];
    }
    __syncthreads();

    // ---- epilogue: waves 0/1 handle pred 0/1 in parallel ----
    const int ew = t >> 6, et = t & 63;

    // log1p + sum over i; subtract the 8 padded-j rows (each added phi_k(0))
    if (ew < 2 && et < NK) {
        const float mu_t = 0.1f * (float)et - 0.95f;
        const float pad  = (et < 20) ? 8.0f * fast_exp2(-72.13475204f * mu_t * mu_t) : 0.0f;
        float s = 0.f;
        #pragma unroll
        for (int i = 0; i < LQ; ++i) {
            const float v = sPhiW[2 * ew][i][et] + sPhiW[2 * ew + 1][i][et] - pad;
            s += __logf(1.0f + v);
        }
        sX[ew][et] = fmaxf(s, 0.f);   // relu (guards tiny negative from pad cancel)
    }
    __syncthreads();

    if (ew < 2 && et < 10) {
        float v = b1[et];
        #pragma unroll
        for (int k = 0; k < NK; ++k) v += W1[et * NK + k] * sX[ew][k];
        sH1[ew][et] = fmaxf(v, 0.f);
    }
    __syncthreads();

    if (ew < 2 && et < 5) {
        float v = b2[et];
        #pragma unroll
        for (int k = 0; k < 10; ++k) v += W2[et * 10 + k] * sH1[ew][k];
        sH2[ew][et] = fmaxf(v, 0.f);
    }
    __syncthreads();

    if (t == 0) {
        float l0 = b3[0], l1 = b3[0];
        #pragma unroll
        for (int k = 0; k < 5; ++k) {
            l0 += W3[k] * sH2[0][k];
            l1 += W3[k] * sH2[1][k];
        }
        out[b] = 1.0f / (1.0f + __expf(l1 - l0));   // sigmoid(l0 - l1)
    }
}

extern "C" void kernel_launch(void* const* d_in, const int* in_sizes, int n_in,
                              void* d_out, int out_size, void* d_ws, size_t ws_size,
                              hipStream_t stream) {
    knrm_main<<<NB, 256, 0, stream>>>(
        (const int*)d_in[0], (const int*)d_in[1],
        (const int*)d_in[2], (const int*)d_in[3],
        (const float*)d_in[4],
        (const float*)d_in[5], (const float*)d_in[6],
        (const float*)d_in[7], (const float*)d_in[8],
        (const float*)d_in[9], (const float*)d_in[10],
        (float*)d_out);
}